// Round 7
// baseline (701.229 us; speedup 1.0000x reference)
//
#include <hip/hip_runtime.h>
#include <hip/hip_bf16.h>
#include <math.h>

// Problem constants
#define H   512
#define E   512
#define B_  256
#define T_  64
#define G4  2048   // 4*H
#define C1  256    // MLP hidden
#define BT  16384  // B*T

#define SPIN_CAP (1 << 22)   // discovery spin bound (dispatch latency)
#define POLL_CAP (1 << 18)   // per-step poll bound: failure -> slow-but-correct
                             // run (R2/R4-proven signature), not a hang

typedef __attribute__((ext_vector_type(8))) short  short8;   // 8 bf16 (4 VGPRs)
typedef __attribute__((ext_vector_type(4))) float  f32x4;    // MFMA acc
typedef __attribute__((ext_vector_type(4))) unsigned short ushort4v;
typedef unsigned short ushort;
typedef unsigned long long u64;

// ---------------------------------------------------------------------------
// Coherence ledger (R2/R3/R4 errata — measured on MI355X, this problem):
//   plain store -> sc0 load, STREAMED line:  works (R0 h-data path).
//   plain store -> sc0 load, POLLED line:    NEVER (sc0 does NOT bypass the
//     consumer L1; polled lines stay L1-resident and stale forever).
//   unflagged atomic -> sc0 load:            NEVER (RMW at MALL, L2 stale).
//   volatile store -> sc0 load:              NEVER (emitted sc0 sc1, MALL).
//   any store/atomic -> AGENT(sc1) load:     works (MALL truth; R0-proven).
// R5: MALL poll CONTENTION refuted (4x traffic cut = no gain). The residual
// step cost is intra-block serialization -> this version removes the block
// from the loop entirely: per-wave signals, no barriers, no LDS tiles.
// R6 syntax errata: offset: immediate must PRECEDE cache flags on gfx950
// (`off offset:64 sc0`, not `off sc0 offset:64`).
// ---------------------------------------------------------------------------

#define BAR_LGKM() asm volatile("s_waitcnt lgkmcnt(0)\n\ts_barrier" ::: "memory")

__device__ __forceinline__ ushort f2bf(float x) {
    unsigned u = __builtin_bit_cast(unsigned, x);
    unsigned r = (u + 0x7FFFu + ((u >> 16) & 1u)) >> 16;
    return (ushort)r;
}
__device__ __forceinline__ float fast_sig(float x) {
    return __builtin_amdgcn_rcpf(1.f + __expf(-x));
}
__device__ __forceinline__ float fast_tanh(float x) {
    return 1.f - 2.f * __builtin_amdgcn_rcpf(1.f + __expf(2.f * x));
}

// 4x 16B fragment loads from one base + byte-offset immediates.
// SC = cache flags: sc0 (local-XCD L2, loc teams) or sc0 sc1 (MALL, fallback).
// offset: BEFORE flags (R6 errata). Issue-only; one drain before use.
#define HLOAD4(SC, b0,b1,b2,b3, base, O0,O1,O2,O3) \
  asm volatile("global_load_dwordx4 %0, %4, off offset:" #O0 " " #SC "\n\t" \
               "global_load_dwordx4 %1, %4, off offset:" #O1 " " #SC "\n\t" \
               "global_load_dwordx4 %2, %4, off offset:" #O2 " " #SC "\n\t" \
               "global_load_dwordx4 %3, %4, off offset:" #O3 " " #SC \
               : "=&v"(b0), "=&v"(b1), "=&v"(b2), "=&v"(b3) \
               : "v"(base) : "memory")

// ---------------------------------------------------------------------------
// P0: fused weight prep — transpose + cast fp32 [K][N] -> bf16 [N][K]
// ---------------------------------------------------------------------------
__global__ __launch_bounds__(256) void prep_weights(
    const float* __restrict__ Wx, const float* __restrict__ Wh,
    const float* __restrict__ W1,
    ushort* __restrict__ WxT, ushort* __restrict__ WhT, ushort* __restrict__ W1T)
{
    __shared__ float t[32][33];
    int bx = blockIdx.x;
    const float* in; ushort* out; int K, N, k0, n0;
    if (bx < 1024)       { in = Wx; out = WxT; K = 512;  N = 2048; k0 = (bx >> 6) * 32; n0 = (bx & 63) * 32; }
    else if (bx < 2048)  { bx -= 1024; in = Wh; out = WhT; K = 512;  N = 2048; k0 = (bx >> 6) * 32; n0 = (bx & 63) * 32; }
    else                 { bx -= 2048; in = W1; out = W1T; K = 1024; N = 256;  k0 = (bx >> 3) * 32; n0 = (bx & 7) * 32; }
    const int tr = threadIdx.x >> 3;
    const int tc = (threadIdx.x & 7) * 4;
    float4 v = *(const float4*)(in + (size_t)(k0 + tr) * N + n0 + tc);
    t[tr][tc + 0] = v.x; t[tr][tc + 1] = v.y; t[tr][tc + 2] = v.z; t[tr][tc + 3] = v.w;
    __syncthreads();
    ushort4v o = { f2bf(t[tc + 0][tr]), f2bf(t[tc + 1][tr]),
                   f2bf(t[tc + 2][tr]), f2bf(t[tc + 3][tr]) };
    *(ushort4v*)(out + (size_t)(n0 + tr) * K + k0 + tc) = o;
}

// ---------------------------------------------------------------------------
// P1: gather X[r,:] = bf16(choice_embed[arg_seq[r], :])
// ---------------------------------------------------------------------------
__global__ __launch_bounds__(128) void gather_embed_bf16(
    const float* __restrict__ emb, const int* __restrict__ idx,
    ushort* __restrict__ X)
{
    const int r = blockIdx.x;
    const int v = idx[r];
    const int c = threadIdx.x * 4;
    float4 f = *(const float4*)(emb + (size_t)v * E + c);
    ushort4v o = { f2bf(f.x), f2bf(f.y), f2bf(f.z), f2bf(f.w) };
    *(ushort4v*)(X + (size_t)r * E + c) = o;
}

// ---------------------------------------------------------------------------
// P2: h0 (bf16) and S[:,0,:] (bf16) from init_state
// ---------------------------------------------------------------------------
__global__ __launch_bounds__(128) void init_prep(
    const float* __restrict__ init, ushort* __restrict__ h0,
    ushort* __restrict__ S)
{
    const int r = blockIdx.x;
    const int c = threadIdx.x * 4;
    float4 f = *(const float4*)(init + (size_t)r * H + c);
    ushort4v o = { f2bf(f.x), f2bf(f.y), f2bf(f.z), f2bf(f.w) };
    *(ushort4v*)(h0 + (size_t)r * H + c) = o;
    *(ushort4v*)(S + ((size_t)r * T_) * H + c) = o;
}

// ---------------------------------------------------------------------------
// P3: zero scores + xcd table + slot arrays (contiguous region)
// ---------------------------------------------------------------------------
__global__ __launch_bounds__(256) void zero_buf(int* p, int n) {
    int i = blockIdx.x * 256 + threadIdx.x;
    if (i < n) p[i] = 0;
}

// ---------------------------------------------------------------------------
// K2: persistent fused LSTM recurrence + fused x@Wx — PER-WAVE dataflow.
// 256 blocks, 1/CU; XCD discovery -> 16-block teams (16 rows each).
// NO barriers, NO LDS tiles in the loop. Each wave:
//   - loads its x fragments direct from global (plain, L1-cached, read-only)
//   - polls 64 per-wave slots (lane l -> slot l, one AGENT load covers the
//     team; R0-proven agent/agent pairing), __all(v >= t)
//   - loads its h B-fragments direct per-lane (sc0 local-L2 / sc0sc1 MALL)
//   - MFMA, epilogue, h-store (plain loc / agent non-loc)
//   - wave-local s_waitcnt vmcnt(0) drain, then agent-stores slot := t+1
// Buffer anti-dependency is enforced by the poll itself: a producer reaches
// iter t+2 (overwriting pp0) only after ALL slots >= t+2, i.e. after every
// reader of pp0@t+1 signaled past its reads. No cross-wave coupling beyond
// the slots -> intra-block barrier/drain serialization is gone, and LDS
// bank conflicts (8.26M/dispatch) vanish with the staging.
// ---------------------------------------------------------------------------
__global__ __launch_bounds__(256, 1) void lstm_fused_main(
    const ushort* __restrict__ WhT, const ushort* __restrict__ WxT,
    const ushort* __restrict__ Xbf, const float* __restrict__ bg,
    const float*  __restrict__ init_state, const ushort* __restrict__ h0,
    ushort* __restrict__ pp0, ushort* __restrict__ pp1,
    ushort* __restrict__ S, int* __restrict__ xcd_tbl, int* __restrict__ cnts)
{
    __shared__ int exl[256];

    const int tid  = threadIdx.x;
    const int wave = tid >> 6, lane = tid & 63;
    const int quad = lane >> 4, l16 = lane & 15;

    // ---- one-time team discovery (bounded) ----
    int xcd;
    asm volatile("s_getreg_b32 %0, hwreg(HW_REG_XCC_ID)" : "=s"(xcd));
    if (tid == 0)
        __hip_atomic_store(&xcd_tbl[blockIdx.x], (xcd & 7) + 1,
                           __ATOMIC_RELAXED, __HIP_MEMORY_SCOPE_AGENT);
    if (wave == 0) {
        for (int it = 0; it < SPIN_CAP; ++it) {
            int miss = 0;
#pragma unroll
            for (int j = 0; j < 4; ++j) {
                int i = lane + j * 64;
                int v = __hip_atomic_load(&xcd_tbl[i], __ATOMIC_RELAXED,
                                          __HIP_MEMORY_SCOPE_AGENT);
                exl[i] = (v == 0) ? 0 : (v - 1);
                if (v == 0) miss = 1;
            }
            if (!__any(miss)) break;
            __builtin_amdgcn_s_sleep(4);
        }
    }
    BAR_LGKM();

    // deterministic assignment (identical scan in every thread)
    int g = 0, m = 0, loc = 0;
    {
        int cntx[8] = {0,0,0,0,0,0,0,0};
        for (int i = 0; i < 256; ++i) cntx[exl[i] & 7]++;
        int take[8], base[8], tA = 0;
        for (int x = 0; x < 8; ++x) {
            int tk = cntx[x] >> 4;
            if (tA + tk > 16) tk = 16 - tA;
            take[x] = tk; base[x] = tA; tA += tk;
        }
        int rc[8] = {0,0,0,0,0,0,0,0}, lc = 0;
        for (int i = 0; i < 256; ++i) {
            int x = exl[i] & 7, r = rc[x]++;
            if ((r >> 4) < take[x]) {
                if (i == (int)blockIdx.x) { g = base[x] + (r >> 4); m = r & 15; loc = 1; }
            } else {
                if (i == (int)blockIdx.x) { g = tA + (lc >> 4); m = lc & 15; loc = 0; }
                lc++;
            }
        }
    }

    const int n0   = g * 16;
    const int jw   = m * 32 + wave * 8;
    const int koff = quad * 8;
    const int ccol = jw + (quad & 1) * 4;
    const int myrow = n0 + l16;

    // A-frag preloads: Wh and Wx (layout validated rounds 2-8)
    short8 af[2][16], ax[2][16];
#pragma unroll
    for (int mf = 0; mf < 2; ++mf) {
        const int gate = mf * 2 + (l16 >> 3);
        const size_t rowoff = (size_t)(gate * 512 + jw + (l16 & 7)) * 512 + koff;
        const ushort* bh = WhT + rowoff;
        const ushort* bx = WxT + rowoff;
#pragma unroll
        for (int kk = 0; kk < 16; ++kk) {
            af[mf][kk] = *(const short8*)(bh + kk * 32);
            ax[mf][kk] = *(const short8*)(bx + kk * 32);
        }
    }

    // bias preload
    float bgi[4], bgf[4], bgg[4], bgo[4];
#pragma unroll
    for (int r = 0; r < 4; ++r) {
        bgi[r] = bg[ccol + r];
        bgf[r] = bg[512 + ccol + r];
        bgg[r] = bg[1024 + ccol + r];
        bgo[r] = bg[1536 + ccol + r];
    }

    // c-state init
    float c[4];
    {
        const float* ip = init_state + (size_t)myrow * H + ccol;
#pragma unroll
        for (int r = 0; r < 4; ++r) c[r] = ip[r];
    }

    // per-wave signal slots: 64 per team (block m, wave w) -> slot m*4+w
    int* slots = cnts + g * 64;            // 256B apart per team
    int* myslotp = slots + m * 4 + wave;
    const int* pollp = slots + lane;       // lane-indexed: one load covers team

    // per-lane x fragment base: row myrow, col koff; step stride = H
    const ushort* xbase = Xbf + ((size_t)myrow * T_) * H + koff;

    for (int t = 0; t < T_ - 1; ++t) {
        // a) x-part: direct per-lane global loads (plain, read-only) + MFMA.
        //    Runs while teammates finish step t-1 (overlaps their signals).
        const ushort* xp = xbase + (size_t)t * H;
        short8 bx[16];
#pragma unroll
        for (int kk = 0; kk < 16; ++kk) bx[kk] = *(const short8*)(xp + kk * 32);
        f32x4 ax0 = {}, ax1 = {};
#pragma unroll
        for (int kk = 0; kk < 16; ++kk) {
            ax0 = __builtin_amdgcn_mfma_f32_16x16x32_bf16(ax[0][kk], bx[kk], ax0, 0, 0, 0);
            ax1 = __builtin_amdgcn_mfma_f32_16x16x32_bf16(ax[1][kk], bx[kk], ax1, 0, 0, 0);
        }

        // b) wait for all 64 producer-waves' h(t): one 64-wide AGENT load
        if (t > 0) {
            for (int it = 0; it < POLL_CAP; ++it) {
                int v = __hip_atomic_load(pollp, __ATOMIC_RELAXED,
                                          __HIP_MEMORY_SCOPE_AGENT);
                if (__all(v >= t)) break;
                __builtin_amdgcn_s_sleep(1);
            }
        }

        // c) h B-fragments: 16 per-lane 16B loads (sc0 local-L2 for loc
        //    teams, sc0sc1 MALL fallback), one drain, sched fence (rule #18)
        const ushort* hin = (t == 0) ? h0 : ((t & 1) ? pp0 : pp1);
        const ushort* hp = hin + (size_t)myrow * H + koff;
        short8 bh[16];
        if (loc) {
            HLOAD4(sc0, bh[0], bh[1], bh[2], bh[3],  hp,   0,  64, 128, 192);
            HLOAD4(sc0, bh[4], bh[5], bh[6], bh[7],  hp, 256, 320, 384, 448);
            HLOAD4(sc0, bh[8], bh[9], bh[10],bh[11], hp, 512, 576, 640, 704);
            HLOAD4(sc0, bh[12],bh[13],bh[14],bh[15], hp, 768, 832, 896, 960);
        } else {
            HLOAD4(sc0 sc1, bh[0], bh[1], bh[2], bh[3],  hp,   0,  64, 128, 192);
            HLOAD4(sc0 sc1, bh[4], bh[5], bh[6], bh[7],  hp, 256, 320, 384, 448);
            HLOAD4(sc0 sc1, bh[8], bh[9], bh[10],bh[11], hp, 512, 576, 640, 704);
            HLOAD4(sc0 sc1, bh[12],bh[13],bh[14],bh[15], hp, 768, 832, 896, 960);
        }
        asm volatile("s_waitcnt vmcnt(0)" ::: "memory");
        __builtin_amdgcn_sched_barrier(0);

        // d) h-part MFMA
        f32x4 a0 = {}, a1 = {};
#pragma unroll
        for (int kk = 0; kk < 16; ++kk) {
            a0 = __builtin_amdgcn_mfma_f32_16x16x32_bf16(af[0][kk], bh[kk], a0, 0, 0, 0);
            a1 = __builtin_amdgcn_mfma_f32_16x16x32_bf16(af[1][kk], bh[kk], a1, 0, 0, 0);
        }

        // e) epilogue: combine, activate, update c
        float hv[4];
#pragma unroll
        for (int r = 0; r < 4; ++r) {
            float v0 = a0[r] + ax0[r], v1 = a1[r] + ax1[r];
            float p0 = __shfl_xor(v0, 32, 64);
            float p1 = __shfl_xor(v1, 32, 64);
            float iv = (quad < 2) ? v0 : p0;
            float fv = (quad < 2) ? p0 : v0;
            float gv = (quad < 2) ? v1 : p1;
            float ov = (quad < 2) ? p1 : v1;
            iv = fast_sig(iv + bgi[r]);
            fv = fast_sig(fv + bgf[r]);
            gv = fast_tanh(gv + bgg[r]);
            ov = fast_sig(ov + bgo[r]);
            float cn = fv * c[r] + iv * gv;
            c[r] = cn;
            hv[r] = ov * fast_tanh(cn);
        }

        // f) h store (exchange buffer): plain for loc (L2-visible to sc0
        //    readers), agent for non-loc (MALL)
        ushort4v o4 = { f2bf(hv[0]), f2bf(hv[1]), f2bf(hv[2]), f2bf(hv[3]) };
        ushort* hout = (t & 1) ? pp1 : pp0;
        if (quad < 2) {
            u64* hp2 = (u64*)(hout + (size_t)myrow * H + ccol);
            if (loc) *hp2 = __builtin_bit_cast(u64, o4);
            else __hip_atomic_store(hp2, __builtin_bit_cast(u64, o4),
                                    __ATOMIC_RELAXED, __HIP_MEMORY_SCOPE_AGENT);
        }

        // g) wave-local drain (vmcnt is per-wave: covers all 32 storing
        //    lanes), then per-wave signal — no block barrier anywhere
        asm volatile("s_waitcnt vmcnt(0)" ::: "memory");
        if (lane == 0)
            __hip_atomic_store(myslotp, t + 1, __ATOMIC_RELAXED,
                               __HIP_MEMORY_SCOPE_AGENT);

        // h) S store AFTER the signal — drained by a later vmcnt(0)
        if (quad < 2)
            *(ushort4v*)(S + ((size_t)myrow * T_ + (t + 1)) * H + ccol) = o4;
    }
}

// ---------------------------------------------------------------------------
// K3: phase C fused with score head.
// ---------------------------------------------------------------------------
__global__ __launch_bounds__(256) void gemm_score(
    const ushort* __restrict__ Sm, const ushort* __restrict__ Xbf,
    const ushort* __restrict__ W1T,   // [256][1024]
    const float* __restrict__ b1, const float* __restrict__ W2,
    float* __restrict__ scores)
{
    const int tid  = threadIdx.x;
    const int wave = tid >> 6, lane = tid & 63;
    const int quad = lane >> 4, l16 = lane & 15;
    const int m0 = blockIdx.y * 128 + wave * 32;
    const int n0 = blockIdx.x * 64;
    const int koff = quad * 8;

    f32x4 acc[2][4] = {};

    for (int src = 0; src < 2; ++src) {
        const ushort* A  = src ? Xbf : Sm;
        const ushort* Bm = W1T + src * 512;
        const ushort* a0p = A + (size_t)(m0 + l16) * H + koff;
        const ushort* a1p = A + (size_t)(m0 + 16 + l16) * H + koff;
        const ushort* bp  = Bm + (size_t)(n0 + l16) * 1024 + koff;
        for (int kk = 0; kk < H; kk += 32) {
            short8 a0 = *(const short8*)(a0p + kk);
            short8 a1 = *(const short8*)(a1p + kk);
#pragma unroll
            for (int nf = 0; nf < 4; ++nf) {
                short8 b = *(const short8*)(bp + (size_t)nf * 16 * 1024 + kk);
                acc[0][nf] = __builtin_amdgcn_mfma_f32_16x16x32_bf16(a0, b, acc[0][nf], 0, 0, 0);
                acc[1][nf] = __builtin_amdgcn_mfma_f32_16x16x32_bf16(a1, b, acc[1][nf], 0, 0, 0);
            }
        }
    }

    float w2v[4], b1v[4];
#pragma unroll
    for (int nf = 0; nf < 4; ++nf) {
        const int col = n0 + nf * 16 + l16;
        w2v[nf] = W2[col];
        b1v[nf] = b1[col];
    }

#pragma unroll
    for (int mf = 0; mf < 2; ++mf) {
#pragma unroll
        for (int r = 0; r < 4; ++r) {
            float p = 0.f;
#pragma unroll
            for (int nf = 0; nf < 4; ++nf)
                p += fmaxf(acc[mf][nf][r] + b1v[nf], 0.f) * w2v[nf];
            p += __shfl_xor(p, 1, 64);
            p += __shfl_xor(p, 2, 64);
            p += __shfl_xor(p, 4, 64);
            p += __shfl_xor(p, 8, 64);
            if (l16 == 0)
                atomicAdd(&scores[m0 + mf * 16 + quad * 4 + r], p);
        }
    }
}

// ---------------------------------------------------------------------------
// K4: out[b] = sum_t (scores[b*T+t] + b2)
// ---------------------------------------------------------------------------
__global__ __launch_bounds__(64) void reduce_scores(
    const float* __restrict__ scores, const float* __restrict__ b2,
    float* __restrict__ out)
{
    const int b    = blockIdx.x;
    const int lane = threadIdx.x;
    float s = scores[(size_t)b * T_ + lane] + b2[0];
#pragma unroll
    for (int off = 32; off; off >>= 1) s += __shfl_xor(s, off, 64);
    if (lane == 0) out[b] = s;
}

// ---------------------------------------------------------------------------
extern "C" void kernel_launch(void* const* d_in, const int* in_sizes, int n_in,
                              void* d_out, int out_size, void* d_ws, size_t ws_size,
                              hipStream_t stream)
{
    const float* init_state = (const float*)d_in[0];
    const float* choice_emb = (const float*)d_in[1];
    const int*   arg_seq    = (const int*)  d_in[2];
    const float* Wx         = (const float*)d_in[3];
    const float* Wh         = (const float*)d_in[4];
    const float* bg         = (const float*)d_in[5];
    const float* W1         = (const float*)d_in[6];
    const float* b1         = (const float*)d_in[7];
    const float* W2         = (const float*)d_in[8];
    const float* b2         = (const float*)d_in[9];
    float* out = (float*)d_out;

    // workspace layout
    ushort* WxT = (ushort*)d_ws;                 // [2048,512] bf16
    ushort* WhT = WxT + 1048576;                 // [2048,512] bf16
    ushort* W1T = WhT + 1048576;                 // [256,1024] bf16
    ushort* Xbf = W1T + 262144;                  // [BT,512]  bf16
    ushort* S   = Xbf + 8388608;                 // [B,T,H]   bf16
    ushort* h0  = S   + 8388608;                 // [B,H]
    ushort* pp0 = h0  + 131072;                  // [B,H]
    ushort* pp1 = pp0 + 131072;                  // [B,H]
    float*  scores  = (float*)(pp1 + 131072);    // [BT]
    int*    xcd_tbl = (int*)(scores + BT);       // [256]
    int*    cnts    = xcd_tbl + 256;             // [16*64] per-wave slots

    // zero scores + table + slots (contiguous ints)
    zero_buf<<<72, 256, 0, stream>>>((int*)scores, BT + 256 + 1024);

    // fused weight prep (Wx, Wh, W1 in one launch)
    prep_weights<<<2304, 256, 0, stream>>>(Wx, Wh, W1, WxT, WhT, W1T);

    // embedding gather -> bf16; state init
    gather_embed_bf16<<<BT, 128, 0, stream>>>(choice_emb, arg_seq, Xbf);
    init_prep<<<B_, 128, 0, stream>>>(init_state, h0, S);

    // Phase A+B fused: persistent recurrence with in-kernel x@Wx
    lstm_fused_main<<<256, 256, 0, stream>>>(
        WhT, WxT, Xbf, bg, init_state, h0, pp0, pp1, S, xcd_tbl, cnts);

    // Phase C+D fused: score accumulation
    gemm_score<<<dim3(C1 / 64, BT / 128), 256, 0, stream>>>(
        S, Xbf, W1T, b1, W2, scores);
    reduce_scores<<<B_, 64, 0, stream>>>(scores, b2, out);
}

// Round 8
// 377.808 us; speedup vs baseline: 1.8560x; 1.8560x over previous
//
#include <hip/hip_runtime.h>
#include <hip/hip_bf16.h>
#include <math.h>

// Problem constants
#define H   512
#define E   512
#define B_  256
#define T_  64
#define G4  2048   // 4*H
#define C1  256    // MLP hidden
#define BT  16384  // B*T

#define SPIN_CAP (1 << 22)   // discovery spin bound (dispatch latency)
#define POLL_CAP (1 << 18)   // per-step poll bound: failure -> slow-but-correct

typedef __attribute__((ext_vector_type(8))) short  short8;   // 8 bf16 (4 VGPRs)
typedef __attribute__((ext_vector_type(4))) float  f32x4;    // MFMA acc
typedef __attribute__((ext_vector_type(4))) int    i32x4;    // 16B granule
typedef __attribute__((ext_vector_type(4))) unsigned short ushort4v;
typedef unsigned short ushort;
typedef unsigned long long u64;

// LDS tile: row-major [row][kc granule], pitch 65 granules (odd) = 520 ushorts.
#define PITCH_US 520

#define BAR_LGKM() asm volatile("s_waitcnt lgkmcnt(0)\n\ts_barrier" ::: "memory")
#define BAR_ALL()  asm volatile("s_waitcnt vmcnt(0) lgkmcnt(0)\n\ts_barrier" ::: "memory")

// ---------------------------------------------------------------------------
// Design ledger (R0-R7, measured on MI355X):
//   - Cross-CU flags MUST go through the MALL (AGENT/sc1 both sides). Local-L2
//     signaling is impossible: sc0 loads never bypass the consumer's L1 on a
//     POLLED line (R4); unflagged atomics and volatile stores bypass the local
//     L2 entirely (R2/R3). Streamed data lines (h) DO work plain->sc0 (R0/R8).
//   - MALL poll contention is NOT a factor (R5: 4x traffic cut = no gain).
//   - Block-lockstep + LDS staging BEATS per-wave dataflow 2.2x (R7):
//     barriers keep team waves phase-aligned; LDS amortizes tile reads.
//   - R8 (this): the residual is 1-wave/SIMD serialization (VALUBusy 27% of a
//     9840cy step is unhidden serial VALU). 512-thread blocks -> 2 waves/SIMD,
//     per-wave tile halved to 4 gates x 4 cols, same team/sync structure.
// ---------------------------------------------------------------------------

__device__ __forceinline__ ushort f2bf(float x) {
    unsigned u = __builtin_bit_cast(unsigned, x);
    unsigned r = (u + 0x7FFFu + ((u >> 16) & 1u)) >> 16;
    return (ushort)r;
}
__device__ __forceinline__ float fast_sig(float x) {
    return __builtin_amdgcn_rcpf(1.f + __expf(-x));
}
__device__ __forceinline__ float fast_tanh(float x) {
    return 1.f - 2.f * __builtin_amdgcn_rcpf(1.f + __expf(2.f * x));
}

// 2x 16B loads, batched, drained. sc0: L1-bypass, local XCD L2 (R8-proven).
#define LOAD2_SC0(v0,v1,p0,p1) \
  asm volatile("global_load_dwordx4 %0, %2, off sc0\n\t" \
               "global_load_dwordx4 %1, %3, off sc0\n\t" \
               "s_waitcnt vmcnt(0)" \
               : "=&v"(v0), "=&v"(v1) : "v"(p0), "v"(p1) : "memory")
#define LOAD2_SC01(v0,v1,p0,p1) \
  asm volatile("global_load_dwordx4 %0, %2, off sc0 sc1\n\t" \
               "global_load_dwordx4 %1, %3, off sc0 sc1\n\t" \
               "s_waitcnt vmcnt(0)" \
               : "=&v"(v0), "=&v"(v1) : "v"(p0), "v"(p1) : "memory")

// ---------------------------------------------------------------------------
// P0: fused weight prep — transpose + cast fp32 [K][N] -> bf16 [N][K]
// ---------------------------------------------------------------------------
__global__ __launch_bounds__(256) void prep_weights(
    const float* __restrict__ Wx, const float* __restrict__ Wh,
    const float* __restrict__ W1,
    ushort* __restrict__ WxT, ushort* __restrict__ WhT, ushort* __restrict__ W1T)
{
    __shared__ float t[32][33];
    int bx = blockIdx.x;
    const float* in; ushort* out; int K, N, k0, n0;
    if (bx < 1024)       { in = Wx; out = WxT; K = 512;  N = 2048; k0 = (bx >> 6) * 32; n0 = (bx & 63) * 32; }
    else if (bx < 2048)  { bx -= 1024; in = Wh; out = WhT; K = 512;  N = 2048; k0 = (bx >> 6) * 32; n0 = (bx & 63) * 32; }
    else                 { bx -= 2048; in = W1; out = W1T; K = 1024; N = 256;  k0 = (bx >> 3) * 32; n0 = (bx & 7) * 32; }
    const int tr = threadIdx.x >> 3;
    const int tc = (threadIdx.x & 7) * 4;
    float4 v = *(const float4*)(in + (size_t)(k0 + tr) * N + n0 + tc);
    t[tr][tc + 0] = v.x; t[tr][tc + 1] = v.y; t[tr][tc + 2] = v.z; t[tr][tc + 3] = v.w;
    __syncthreads();
    ushort4v o = { f2bf(t[tc + 0][tr]), f2bf(t[tc + 1][tr]),
                   f2bf(t[tc + 2][tr]), f2bf(t[tc + 3][tr]) };
    *(ushort4v*)(out + (size_t)(n0 + tr) * K + k0 + tc) = o;
}

// ---------------------------------------------------------------------------
// P1: gather X[r,:] = bf16(choice_embed[arg_seq[r], :])
// ---------------------------------------------------------------------------
__global__ __launch_bounds__(128) void gather_embed_bf16(
    const float* __restrict__ emb, const int* __restrict__ idx,
    ushort* __restrict__ X)
{
    const int r = blockIdx.x;
    const int v = idx[r];
    const int c = threadIdx.x * 4;
    float4 f = *(const float4*)(emb + (size_t)v * E + c);
    ushort4v o = { f2bf(f.x), f2bf(f.y), f2bf(f.z), f2bf(f.w) };
    *(ushort4v*)(X + (size_t)r * E + c) = o;
}

// ---------------------------------------------------------------------------
// P2: h0 (bf16) and S[:,0,:] (bf16) from init_state
// ---------------------------------------------------------------------------
__global__ __launch_bounds__(128) void init_prep(
    const float* __restrict__ init, ushort* __restrict__ h0,
    ushort* __restrict__ S)
{
    const int r = blockIdx.x;
    const int c = threadIdx.x * 4;
    float4 f = *(const float4*)(init + (size_t)r * H + c);
    ushort4v o = { f2bf(f.x), f2bf(f.y), f2bf(f.z), f2bf(f.w) };
    *(ushort4v*)(h0 + (size_t)r * H + c) = o;
    *(ushort4v*)(S + ((size_t)r * T_) * H + c) = o;
}

// ---------------------------------------------------------------------------
// P3: zero scores + xcd table + counters (contiguous region)
// ---------------------------------------------------------------------------
__global__ __launch_bounds__(256) void zero_buf(int* p, int n) {
    int i = blockIdx.x * 256 + threadIdx.x;
    if (i < n) p[i] = 0;
}

// ---------------------------------------------------------------------------
// K2: persistent fused LSTM recurrence + fused x@Wx.
// 256 blocks x 512 threads (8 waves) = 1 block/CU, 2 waves/SIMD (the R8
// lever: a lone wave/SIMD cannot hide its own VALU/LDS/poll stalls; two
// interleave). XCD discovery -> 16-block teams. Per-wave tile: 4 gates x
// 4 cols (gate = l16>>2, col = jw+(l16&3), jw = m*32+wave*4); epilogue
// gathers i,f,g,o per (row,col) via a 4x4 quad-transpose (3 shfl_xor).
// Sync/staging identical to the proven R0 structure: LDS odd-pitch tiles,
// BAR_ALL + tid0 atomicAdd team counter, all-wave AGENT poll.
// ---------------------------------------------------------------------------
__global__ __launch_bounds__(512, 2) void lstm_fused_main(
    const ushort* __restrict__ WhT, const ushort* __restrict__ WxT,
    const ushort* __restrict__ Xbf, const float* __restrict__ bg,
    const float*  __restrict__ init_state, const ushort* __restrict__ h0,
    ushort* __restrict__ pp0, ushort* __restrict__ pp1,
    ushort* __restrict__ S, int* __restrict__ xcd_tbl, int* __restrict__ cnts)
{
    __shared__ __align__(16) ushort hsh[16 * PITCH_US];
    __shared__ __align__(16) ushort xsh[2][16 * PITCH_US];
    __shared__ int exl[256];

    const int tid  = threadIdx.x;
    const int wave = tid >> 6, lane = tid & 63;
    const int quad = lane >> 4, l16 = lane & 15;

    // ---- one-time team discovery (bounded) ----
    int xcd;
    asm volatile("s_getreg_b32 %0, hwreg(HW_REG_XCC_ID)" : "=s"(xcd));
    if (tid == 0)
        __hip_atomic_store(&xcd_tbl[blockIdx.x], (xcd & 7) + 1,
                           __ATOMIC_RELAXED, __HIP_MEMORY_SCOPE_AGENT);
    if (wave == 0) {
        for (int it = 0; it < SPIN_CAP; ++it) {
            int miss = 0;
#pragma unroll
            for (int j = 0; j < 4; ++j) {
                int i = lane + j * 64;
                int v = __hip_atomic_load(&xcd_tbl[i], __ATOMIC_RELAXED,
                                          __HIP_MEMORY_SCOPE_AGENT);
                exl[i] = (v == 0) ? 0 : (v - 1);
                if (v == 0) miss = 1;
            }
            if (!__any(miss)) break;
            __builtin_amdgcn_s_sleep(4);
        }
    }
    BAR_LGKM();

    // deterministic assignment (identical scan in every thread)
    int g = 0, m = 0, loc = 0;
    {
        int cntx[8] = {0,0,0,0,0,0,0,0};
        for (int i = 0; i < 256; ++i) cntx[exl[i] & 7]++;
        int take[8], base[8], tA = 0;
        for (int x = 0; x < 8; ++x) {
            int tk = cntx[x] >> 4;
            if (tA + tk > 16) tk = 16 - tA;
            take[x] = tk; base[x] = tA; tA += tk;
        }
        int rc[8] = {0,0,0,0,0,0,0,0}, lc = 0;
        for (int i = 0; i < 256; ++i) {
            int x = exl[i] & 7, r = rc[x]++;
            if ((r >> 4) < take[x]) {
                if (i == (int)blockIdx.x) { g = base[x] + (r >> 4); m = r & 15; loc = 1; }
            } else {
                if (i == (int)blockIdx.x) { g = tA + (lc >> 4); m = lc & 15; loc = 0; }
                lc++;
            }
        }
    }

    const int n0    = g * 16;
    const int jw    = m * 32 + wave * 4;   // wave's 4 hidden-cols
    const int koff  = quad * 8;
    const int myrow = n0 + l16;
    const int hcol  = jw + quad;           // this thread's output hidden-col

    // A-frag preloads: one tile = 4 gates x 4 cols.
    // A-row l16 -> gate = l16>>2, col = jw + (l16&3). K chunk = koff + kk*32.
    short8 af[16], ax[16];
    {
        const size_t rowoff =
            (size_t)((l16 >> 2) * 512 + jw + (l16 & 3)) * 512 + koff;
        const ushort* bh = WhT + rowoff;
        const ushort* bx = WxT + rowoff;
#pragma unroll
        for (int kk = 0; kk < 16; ++kk) {
            af[kk] = *(const short8*)(bh + kk * 32);
            ax[kk] = *(const short8*)(bx + kk * 32);
        }
    }

    // bias: gate = quad, cols jw..jw+3 (added pre-transpose)
    float bgq[4];
#pragma unroll
    for (int r = 0; r < 4; ++r) bgq[r] = bg[quad * 512 + jw + r];

    // c-state: one (row, col) per thread
    float c1 = init_state[(size_t)myrow * H + hcol];

    // staging coords: 2 granules of 16B per thread (512 thr x 2 = 16x64)
    int gr[2], gc[2], lo[2];
#pragma unroll
    for (int j = 0; j < 2; ++j) {
        int lin = tid + j * 512;
        gr[j] = lin >> 6; gc[j] = lin & 63;
        lo[j] = gr[j] * PITCH_US + gc[j] * 8;
    }

    // stage x(0) into xsh[0]
#pragma unroll
    for (int j = 0; j < 2; ++j) {
        i32x4 v = *(const i32x4*)(Xbf + ((size_t)(n0 + gr[j]) * T_) * H + gc[j] * 8);
        *(i32x4*)&xsh[0][lo[j]] = v;
    }
    BAR_LGKM();

    int* cnt = cnts + g * 32;                          // 128B apart per team
    const int frag_base = l16 * PITCH_US + quad * 8;   // + kk*32

    for (int t = 0; t < T_ - 1; ++t) {
        // a) issue x(t+1) prefetch (plain cached loads)
        i32x4 xv0, xv1;
        const int have_x = (t + 1 < T_ - 1);
        if (have_x) {
            xv0 = *(const i32x4*)(Xbf + ((size_t)(n0 + gr[0]) * T_ + t + 1) * H + gc[0] * 8);
            xv1 = *(const i32x4*)(Xbf + ((size_t)(n0 + gr[1]) * T_ + t + 1) * H + gc[1] * 8);
        }

        // b) x-part MFMA (independent of h -> overlaps the wait)
        f32x4 axx = {};
        {
            const ushort* xb = xsh[t & 1];
#pragma unroll
            for (int kk = 0; kk < 16; ++kk) {
                short8 b = *(const short8*)&xb[frag_base + kk * 32];
                axx = __builtin_amdgcn_mfma_f32_16x16x32_bf16(ax[kk], b, axx, 0, 0, 0);
            }
        }

        // c) wait for teammates' h(t): every wave polls the team counter
        if (t > 0) {
            const int tgt = t << 4;
            for (int it = 0; it < POLL_CAP; ++it) {
                if (__hip_atomic_load(cnt, __ATOMIC_RELAXED,
                                      __HIP_MEMORY_SCOPE_AGENT) >= tgt) break;
                __builtin_amdgcn_s_sleep(1);
            }
        }

        // d) stage h(t) into LDS (16B loads; local L2 for loc teams)
        {
            const ushort* hin = (t == 0) ? h0 : ((t & 1) ? pp0 : pp1);
            const ushort* p0 = hin + (size_t)(n0 + gr[0]) * H + gc[0] * 8;
            const ushort* p1 = hin + (size_t)(n0 + gr[1]) * H + gc[1] * 8;
            i32x4 v0, v1;
            if (loc) { LOAD2_SC0(v0, v1, p0, p1); }
            else     { LOAD2_SC01(v0, v1, p0, p1); }
            *(i32x4*)&hsh[lo[0]] = v0;
            *(i32x4*)&hsh[lo[1]] = v1;
        }
        BAR_LGKM();

        // e) h-part MFMA
        f32x4 ah = {};
#pragma unroll
        for (int kk = 0; kk < 16; ++kk) {
            short8 b = *(const short8*)&hsh[frag_base + kk * 32];
            ah = __builtin_amdgcn_mfma_f32_16x16x32_bf16(af[kk], b, ah, 0, 0, 0);
        }

        // f) write x(t+1) into the other xsh buffer
        if (have_x) {
            ushort* xb = xsh[(t + 1) & 1];
            *(i32x4*)&xb[lo[0]] = xv0;
            *(i32x4*)&xb[lo[1]] = xv1;
        }

        // g) epilogue. g4[r] = preact[gate=quad][col jw+r][row l16].
        //    4x4 quad-transpose: round m sends g4[quad^m] across lane^(16m);
        //    receiver q gets gate (q^m)'s value at col jw+q. Verified mapping:
        //    i=recv[q], f=recv[q^1], g=recv[q^2], o=recv[q^3].
        float g4[4];
#pragma unroll
        for (int r = 0; r < 4; ++r) g4[r] = ah[r] + axx[r] + bgq[r];
        float s1 = (quad & 1) ? ((quad & 2) ? g4[2] : g4[0])
                              : ((quad & 2) ? g4[3] : g4[1]);
        float s2 = (quad & 2) ? ((quad & 1) ? g4[1] : g4[0])
                              : ((quad & 1) ? g4[3] : g4[2]);
        float s3 = (quad & 2) ? ((quad & 1) ? g4[0] : g4[1])
                              : ((quad & 1) ? g4[2] : g4[3]);
        float r0 = (quad & 1) ? ((quad & 2) ? g4[3] : g4[1])
                              : ((quad & 2) ? g4[2] : g4[0]);
        float r1 = __shfl_xor(s1, 16, 64);
        float r2 = __shfl_xor(s2, 32, 64);
        float r3 = __shfl_xor(s3, 48, 64);
        float iv = (quad == 0) ? r0 : (quad == 1) ? r1 : (quad == 2) ? r2 : r3;
        float fv = (quad == 0) ? r1 : (quad == 1) ? r0 : (quad == 2) ? r3 : r2;
        float gv = (quad == 0) ? r2 : (quad == 1) ? r3 : (quad == 2) ? r0 : r1;
        float ov = (quad == 0) ? r3 : (quad == 1) ? r2 : (quad == 2) ? r1 : r0;
        iv = fast_sig(iv);
        fv = fast_sig(fv);
        gv = fast_tanh(gv);
        ov = fast_sig(ov);
        float cn = fv * c1 + iv * gv;
        c1 = cn;
        ushort ho = f2bf(ov * fast_tanh(cn));

        // h) h store (exchange buffer): 2B per lane, every lane distinct
        ushort* hout = (t & 1) ? pp1 : pp0;
        {
            ushort* hp2 = hout + (size_t)myrow * H + hcol;
            if (loc) *hp2 = ho;
            else asm volatile("global_store_short %0, %1, off sc0 sc1"
                              :: "v"(hp2), "v"((int)ho) : "memory");
        }

        // i) drain h store, block barrier, signal via device-scope atomic
        BAR_ALL();
        if (tid == 0) atomicAdd(cnt, 1);

        // j) S store AFTER the signal — drained by a later vmcnt(0)
        S[((size_t)myrow * T_ + (t + 1)) * H + hcol] = ho;
    }
}

// ---------------------------------------------------------------------------
// K3: phase C fused with score head.
// ---------------------------------------------------------------------------
__global__ __launch_bounds__(256) void gemm_score(
    const ushort* __restrict__ Sm, const ushort* __restrict__ Xbf,
    const ushort* __restrict__ W1T,   // [256][1024]
    const float* __restrict__ b1, const float* __restrict__ W2,
    float* __restrict__ scores)
{
    const int tid  = threadIdx.x;
    const int wave = tid >> 6, lane = tid & 63;
    const int quad = lane >> 4, l16 = lane & 15;
    const int m0 = blockIdx.y * 128 + wave * 32;
    const int n0 = blockIdx.x * 64;
    const int koff = quad * 8;

    f32x4 acc[2][4] = {};

    for (int src = 0; src < 2; ++src) {
        const ushort* A  = src ? Xbf : Sm;
        const ushort* Bm = W1T + src * 512;
        const ushort* a0p = A + (size_t)(m0 + l16) * H + koff;
        const ushort* a1p = A + (size_t)(m0 + 16 + l16) * H + koff;
        const ushort* bp  = Bm + (size_t)(n0 + l16) * 1024 + koff;
        for (int kk = 0; kk < H; kk += 32) {
            short8 a0 = *(const short8*)(a0p + kk);
            short8 a1 = *(const short8*)(a1p + kk);
#pragma unroll
            for (int nf = 0; nf < 4; ++nf) {
                short8 b = *(const short8*)(bp + (size_t)nf * 16 * 1024 + kk);
                acc[0][nf] = __builtin_amdgcn_mfma_f32_16x16x32_bf16(a0, b, acc[0][nf], 0, 0, 0);
                acc[1][nf] = __builtin_amdgcn_mfma_f32_16x16x32_bf16(a1, b, acc[1][nf], 0, 0, 0);
            }
        }
    }

    float w2v[4], b1v[4];
#pragma unroll
    for (int nf = 0; nf < 4; ++nf) {
        const int col = n0 + nf * 16 + l16;
        w2v[nf] = W2[col];
        b1v[nf] = b1[col];
    }

#pragma unroll
    for (int mf = 0; mf < 2; ++mf) {
#pragma unroll
        for (int r = 0; r < 4; ++r) {
            float p = 0.f;
#pragma unroll
            for (int nf = 0; nf < 4; ++nf)
                p += fmaxf(acc[mf][nf][r] + b1v[nf], 0.f) * w2v[nf];
            p += __shfl_xor(p, 1, 64);
            p += __shfl_xor(p, 2, 64);
            p += __shfl_xor(p, 4, 64);
            p += __shfl_xor(p, 8, 64);
            if (l16 == 0)
                atomicAdd(&scores[m0 + mf * 16 + quad * 4 + r], p);
        }
    }
}

// ---------------------------------------------------------------------------
// K4: out[b] = sum_t (scores[b*T+t] + b2)
// ---------------------------------------------------------------------------
__global__ __launch_bounds__(64) void reduce_scores(
    const float* __restrict__ scores, const float* __restrict__ b2,
    float* __restrict__ out)
{
    const int b    = blockIdx.x;
    const int lane = threadIdx.x;
    float s = scores[(size_t)b * T_ + lane] + b2[0];
#pragma unroll
    for (int off = 32; off; off >>= 1) s += __shfl_xor(s, off, 64);
    if (lane == 0) out[b] = s;
}

// ---------------------------------------------------------------------------
extern "C" void kernel_launch(void* const* d_in, const int* in_sizes, int n_in,
                              void* d_out, int out_size, void* d_ws, size_t ws_size,
                              hipStream_t stream)
{
    const float* init_state = (const float*)d_in[0];
    const float* choice_emb = (const float*)d_in[1];
    const int*   arg_seq    = (const int*)  d_in[2];
    const float* Wx         = (const float*)d_in[3];
    const float* Wh         = (const float*)d_in[4];
    const float* bg         = (const float*)d_in[5];
    const float* W1         = (const float*)d_in[6];
    const float* b1         = (const float*)d_in[7];
    const float* W2         = (const float*)d_in[8];
    const float* b2         = (const float*)d_in[9];
    float* out = (float*)d_out;

    // workspace layout
    ushort* WxT = (ushort*)d_ws;                 // [2048,512] bf16
    ushort* WhT = WxT + 1048576;                 // [2048,512] bf16
    ushort* W1T = WhT + 1048576;                 // [256,1024] bf16
    ushort* Xbf = W1T + 262144;                  // [BT,512]  bf16
    ushort* S   = Xbf + 8388608;                 // [B,T,H]   bf16
    ushort* h0  = S   + 8388608;                 // [B,H]
    ushort* pp0 = h0  + 131072;                  // [B,H]
    ushort* pp1 = pp0 + 131072;                  // [B,H]
    float*  scores  = (float*)(pp1 + 131072);    // [BT]
    int*    xcd_tbl = (int*)(scores + BT);       // [256]
    int*    cnts    = xcd_tbl + 256;             // [16*32]

    // zero scores + table + counters (contiguous ints)
    zero_buf<<<70, 256, 0, stream>>>((int*)scores, BT + 256 + 512);

    // fused weight prep (Wx, Wh, W1 in one launch)
    prep_weights<<<2304, 256, 0, stream>>>(Wx, Wh, W1, WxT, WhT, W1T);

    // embedding gather -> bf16; state init
    gather_embed_bf16<<<BT, 128, 0, stream>>>(choice_emb, arg_seq, Xbf);
    init_prep<<<B_, 128, 0, stream>>>(init_state, h0, S);

    // Phase A+B fused: persistent recurrence with in-kernel x@Wx
    lstm_fused_main<<<256, 512, 0, stream>>>(
        WhT, WxT, Xbf, bg, init_state, h0, pp0, pp1, S, xcd_tbl, cnts);

    // Phase C+D fused: score accumulation
    gemm_score<<<dim3(C1 / 64, BT / 128), 256, 0, stream>>>(
        S, Xbf, W1T, b1, W2, scores);
    reduce_scores<<<B_, 64, 0, stream>>>(scores, b2, out);
}